// Round 1
// baseline (69.971 us; speedup 1.0000x reference)
//
#include <hip/hip_runtime.h>

#define NPTS  16384
#define BLOCK 256
#define PPT   8      // row points per thread
#define TC    256    // col points per block tile

// combined(i,j) = ALPHA*|dxyz|^2 + BETA*(dp)^2, ALPHA=1, BETA=0.5
//              = Pn_i + Tn_j - 2*(x*tx + y*ty + z*tz) - pp*tp
// Pn_i = x^2+y^2+z^2 + 0.5*pp^2 ;  Tn_j likewise.
// Per-row min: Pn_i folds out of the min, added at the end.

__global__ __launch_bounds__(BLOCK) void chamfer_min_kernel(
    const float4* __restrict__ pred,
    const float4* __restrict__ target,
    unsigned int* __restrict__ minbuf)   // [2*NPTS] float bits, pre-init huge
{
    const float4* A;
    const float4* B;
    unsigned int* mb;
    if (blockIdx.z == 0) { A = pred;   B = target; mb = minbuf; }
    else                 { A = target; B = pred;   mb = minbuf + NPTS; }

    __shared__ __align__(16) float stx[TC], sty[TC], stz[TC], stp[TC], stn[TC];

    const int colBase = blockIdx.y * TC;
    for (int j = threadIdx.x; j < TC; j += BLOCK) {
        float4 t = B[colBase + j];
        stx[j] = t.x; sty[j] = t.y; stz[j] = t.z; stp[j] = t.w;
        stn[j] = fmaf(t.x, t.x, fmaf(t.y, t.y, fmaf(t.z, t.z, 0.5f * t.w * t.w)));
    }
    __syncthreads();

    const int rowBase = blockIdx.x * (BLOCK * PPT) + threadIdx.x;

    float X[PPT], Y[PPT], Z[PPT], W[PPT], Pn[PPT], m[PPT];
#pragma unroll
    for (int k = 0; k < PPT; ++k) {
        float4 p = A[rowBase + k * BLOCK];
        X[k] = -2.0f * p.x;
        Y[k] = -2.0f * p.y;
        Z[k] = -2.0f * p.z;
        W[k] = -p.w;
        Pn[k] = fmaf(p.x, p.x, fmaf(p.y, p.y, fmaf(p.z, p.z, 0.5f * p.w * p.w)));
        m[k] = 3.0e38f;
    }

    for (int j = 0; j < TC; j += 4) {
        const float4 tx = *reinterpret_cast<const float4*>(stx + j);
        const float4 ty = *reinterpret_cast<const float4*>(sty + j);
        const float4 tz = *reinterpret_cast<const float4*>(stz + j);
        const float4 tp = *reinterpret_cast<const float4*>(stp + j);
        const float4 tn = *reinterpret_cast<const float4*>(stn + j);
#pragma unroll
        for (int k = 0; k < PPT; ++k) {
            float s0 = fmaf(X[k], tx.x, tn.x); s0 = fmaf(Y[k], ty.x, s0); s0 = fmaf(Z[k], tz.x, s0); s0 = fmaf(W[k], tp.x, s0);
            float s1 = fmaf(X[k], tx.y, tn.y); s1 = fmaf(Y[k], ty.y, s1); s1 = fmaf(Z[k], tz.y, s1); s1 = fmaf(W[k], tp.y, s1);
            float s2 = fmaf(X[k], tx.z, tn.z); s2 = fmaf(Y[k], ty.z, s2); s2 = fmaf(Z[k], tz.z, s2); s2 = fmaf(W[k], tp.z, s2);
            float s3 = fmaf(X[k], tx.w, tn.w); s3 = fmaf(Y[k], ty.w, s3); s3 = fmaf(Z[k], tz.w, s3); s3 = fmaf(W[k], tp.w, s3);
            // hope for v_min3_f32 fusion
            m[k] = fminf(fminf(m[k], s0), s1);
            m[k] = fminf(fminf(m[k], s2), s3);
        }
    }

#pragma unroll
    for (int k = 0; k < PPT; ++k) {
        float v = fmaxf(m[k] + Pn[k], 0.0f);   // ref clamps dist at >= 0
        atomicMin(&mb[rowBase + k * BLOCK], __float_as_uint(v));
    }
}

__global__ __launch_bounds__(1024) void chamfer_reduce_kernel(
    const unsigned int* __restrict__ minbuf, float* __restrict__ out)
{
    __shared__ float red[16];
    float s = 0.0f;
    for (int i = threadIdx.x; i < 2 * NPTS; i += 1024)
        s += __uint_as_float(minbuf[i]);
    // wave-64 tree reduce
#pragma unroll
    for (int off = 32; off > 0; off >>= 1)
        s += __shfl_down(s, off);
    const int wave = threadIdx.x >> 6;
    const int lane = threadIdx.x & 63;
    if (lane == 0) red[wave] = s;
    __syncthreads();
    if (threadIdx.x == 0) {
        float t = 0.0f;
#pragma unroll
        for (int w = 0; w < 16; ++w) t += red[w];
        out[0] = t * (1.0f / (float)NPTS);
    }
}

extern "C" void kernel_launch(void* const* d_in, const int* in_sizes, int n_in,
                              void* d_out, int out_size, void* d_ws, size_t ws_size,
                              hipStream_t stream) {
    const float4* pred   = (const float4*)d_in[0];
    const float4* target = (const float4*)d_in[1];
    unsigned int* minbuf = (unsigned int*)d_ws;

    // 0x7f7f7f7f == 3.39e38f > any real distance; graph-capture-safe memset
    hipMemsetAsync(d_ws, 0x7f, 2 * NPTS * sizeof(unsigned int), stream);

    dim3 grid(NPTS / (BLOCK * PPT), NPTS / TC, 2);   // (8, 64, 2)
    chamfer_min_kernel<<<grid, BLOCK, 0, stream>>>(pred, target, minbuf);
    chamfer_reduce_kernel<<<1, 1024, 0, stream>>>((const unsigned int*)d_ws,
                                                  (float*)d_out);
}

// Round 2
// 68.384 us; speedup vs baseline: 1.0232x; 1.0232x over previous
//
#include <hip/hip_runtime.h>

#define NPTS  16384
#define BLOCK 256
#define PPT   8      // row points per thread
#define TC    256    // col points per block tile

typedef float v2f __attribute__((ext_vector_type(2)));

// Full-rate packed FP32 FMA (gfx90a+/CDNA4). Default VOP3P modifiers:
// d.lo = fma(a.lo,b.lo,c.lo); d.hi = fma(a.hi,b.hi,c.hi)
__device__ __forceinline__ v2f pk_fma(v2f a, v2f b, v2f c) {
    v2f d;
    asm("v_pk_fma_f32 %0, %1, %2, %3" : "=v"(d) : "v"(a), "v"(b), "v"(c));
    return d;
}

// combined(i,j) = Pn_i + Tn_j - 2*(x*tx+y*ty+z*tz) - pp*tp
// Pn_i = |xyz_i|^2 + 0.5*pp_i^2 ; Tn_j likewise. Pn_i folds out of the min.

__global__ __launch_bounds__(BLOCK) void chamfer_min_kernel(
    const float4* __restrict__ pred,
    const float4* __restrict__ target,
    unsigned int* __restrict__ minbuf)   // [2*NPTS] float bits, pre-init huge
{
    const float4* A;
    const float4* B;
    unsigned int* mb;
    if (blockIdx.z == 0) { A = pred;   B = target; mb = minbuf; }
    else                 { A = target; B = pred;   mb = minbuf + NPTS; }

    __shared__ __align__(16) float stx[TC], sty[TC], stz[TC], stp[TC], stn[TC];

    const int colBase = blockIdx.y * TC;
    for (int j = threadIdx.x; j < TC; j += BLOCK) {
        float4 t = B[colBase + j];
        stx[j] = t.x; sty[j] = t.y; stz[j] = t.z; stp[j] = t.w;
        stn[j] = fmaf(t.x, t.x, fmaf(t.y, t.y, fmaf(t.z, t.z, 0.5f * t.w * t.w)));
    }
    __syncthreads();

    const int rowBase = blockIdx.x * (BLOCK * PPT) + threadIdx.x;

    v2f Xp[PPT], Yp[PPT], Zp[PPT], Wp[PPT];
    float Pn[PPT], m[PPT];
#pragma unroll
    for (int k = 0; k < PPT; ++k) {
        float4 p = A[rowBase + k * BLOCK];
        float x = -2.0f * p.x, y = -2.0f * p.y, z = -2.0f * p.z, w = -p.w;
        Xp[k] = (v2f){x, x};
        Yp[k] = (v2f){y, y};
        Zp[k] = (v2f){z, z};
        Wp[k] = (v2f){w, w};
        Pn[k] = fmaf(p.x, p.x, fmaf(p.y, p.y, fmaf(p.z, p.z, 0.5f * p.w * p.w)));
        m[k] = 3.0e38f;
    }

#pragma unroll 2
    for (int j = 0; j < TC; j += 4) {
        const float4 txq = *reinterpret_cast<const float4*>(stx + j);
        const float4 tyq = *reinterpret_cast<const float4*>(sty + j);
        const float4 tzq = *reinterpret_cast<const float4*>(stz + j);
        const float4 tpq = *reinterpret_cast<const float4*>(stp + j);
        const float4 tnq = *reinterpret_cast<const float4*>(stn + j);
        const v2f tx01 = {txq.x, txq.y}, tx23 = {txq.z, txq.w};
        const v2f ty01 = {tyq.x, tyq.y}, ty23 = {tyq.z, tyq.w};
        const v2f tz01 = {tzq.x, tzq.y}, tz23 = {tzq.z, tzq.w};
        const v2f tp01 = {tpq.x, tpq.y}, tp23 = {tpq.z, tpq.w};
        const v2f tn01 = {tnq.x, tnq.y}, tn23 = {tnq.z, tnq.w};
#pragma unroll
        for (int k = 0; k < PPT; ++k) {
            v2f s01 = pk_fma(Wp[k], tp01, tn01);
            s01 = pk_fma(Zp[k], tz01, s01);
            s01 = pk_fma(Yp[k], ty01, s01);
            s01 = pk_fma(Xp[k], tx01, s01);
            v2f s23 = pk_fma(Wp[k], tp23, tn23);
            s23 = pk_fma(Zp[k], tz23, s23);
            s23 = pk_fma(Yp[k], ty23, s23);
            s23 = pk_fma(Xp[k], tx23, s23);
            // fminf chains should fuse to v_min3_f32
            m[k] = fminf(fminf(m[k], s01.x), s01.y);
            m[k] = fminf(fminf(m[k], s23.x), s23.y);
        }
    }

#pragma unroll
    for (int k = 0; k < PPT; ++k) {
        float v = fmaxf(m[k] + Pn[k], 0.0f);   // ref clamps dist at >= 0
        atomicMin(&mb[rowBase + k * BLOCK], __float_as_uint(v));
    }
}

__global__ __launch_bounds__(1024) void chamfer_reduce_kernel(
    const unsigned int* __restrict__ minbuf, float* __restrict__ out)
{
    __shared__ float red[16];
    float s = 0.0f;
    for (int i = threadIdx.x; i < 2 * NPTS; i += 1024)
        s += __uint_as_float(minbuf[i]);
#pragma unroll
    for (int off = 32; off > 0; off >>= 1)
        s += __shfl_down(s, off);
    const int wave = threadIdx.x >> 6;
    const int lane = threadIdx.x & 63;
    if (lane == 0) red[wave] = s;
    __syncthreads();
    if (threadIdx.x == 0) {
        float t = 0.0f;
#pragma unroll
        for (int w = 0; w < 16; ++w) t += red[w];
        out[0] = t * (1.0f / (float)NPTS);
    }
}

extern "C" void kernel_launch(void* const* d_in, const int* in_sizes, int n_in,
                              void* d_out, int out_size, void* d_ws, size_t ws_size,
                              hipStream_t stream) {
    const float4* pred   = (const float4*)d_in[0];
    const float4* target = (const float4*)d_in[1];
    unsigned int* minbuf = (unsigned int*)d_ws;

    // 0x7f7f7f7f == 3.39e38f > any real distance; graph-capture-safe memset
    hipMemsetAsync(d_ws, 0x7f, 2 * NPTS * sizeof(unsigned int), stream);

    dim3 grid(NPTS / (BLOCK * PPT), NPTS / TC, 2);   // (8, 64, 2)
    chamfer_min_kernel<<<grid, BLOCK, 0, stream>>>(pred, target, minbuf);
    chamfer_reduce_kernel<<<1, 1024, 0, stream>>>((const unsigned int*)d_ws,
                                                  (float*)d_out);
}

// Round 4
// 44.048 us; speedup vs baseline: 1.5885x; 1.5525x over previous
//
#include <hip/hip_runtime.h>

#define NPTS   16384
#define RPB    256      // rows per block (4 waves x 64)
#define RPW    64       // rows per wave (2 row-tiles of 32)
#define CHUNK  2048     // cols per block sweep
#define NCHUNK (NPTS / CHUNK)   // 8
#define NRB    (NPTS / RPB)     // 64

typedef short  bf16x8 __attribute__((ext_vector_type(8)));
typedef float  f32x16 __attribute__((ext_vector_type(16)));

// ---- bf16 split helpers (RNE, no API dependence) ----
__device__ __forceinline__ unsigned rne_bf16(float f) {
    unsigned u = __float_as_uint(f);
    return (u + 0x7fffu + ((u >> 16) & 1u)) >> 16;
}
__device__ __forceinline__ float bf16_dec(unsigned h) {
    return __uint_as_float(h << 16);
}
#define ONE_BF 0x3f80u

// K=16 slot map (A = row side / weighted, B = col side / plain):
//  k0-3 : ah*bh   k4-7: al*bh   k8-11: ah*bl
//  k12  : 1*Tnh   k13 : 1*Tnl   k14: Pnh*1   k15: Pnl*1
// => acc = hi-precision dot + Tn_j + Pn_i = combined(i,j) directly.
// Record layout per point: 2 x bf16x8 (lane<32 reads rec[0], lane>=32 rec[1]).
// (Both candidate A/B k-layout conventions produce this same product set.)

__global__ __launch_bounds__(256) void prep_kernel(
    const float4* __restrict__ pred, const float4* __restrict__ tgt,
    uint4* __restrict__ wpred, uint4* __restrict__ ptgt,
    uint4* __restrict__ wtgt,  uint4* __restrict__ ppred)
{
    int i = blockIdx.x * 256 + threadIdx.x;
    if (i >= NPTS) return;

    float4 pts[2] = { pred[i], tgt[i] };

#pragma unroll
    for (int s = 0; s < 2; ++s) {
        float4 v = pts[s];
        float n = fmaf(v.x, v.x, fmaf(v.y, v.y, fmaf(v.z, v.z, 0.5f * v.w * v.w)));
        unsigned nh = rne_bf16(n);
        unsigned nl = rne_bf16(n - bf16_dec(nh));
        unsigned npk = nh | (nl << 16);
        unsigned onepk = ONE_BF | (ONE_BF << 16);

        // weighted row-side record (from this point set)
        float w0 = -2.0f * v.x, w1 = -2.0f * v.y, w2 = -2.0f * v.z, w3 = -v.w;
        unsigned h0 = rne_bf16(w0), h1 = rne_bf16(w1), h2 = rne_bf16(w2), h3 = rne_bf16(w3);
        unsigned l0 = rne_bf16(w0 - bf16_dec(h0)), l1 = rne_bf16(w1 - bf16_dec(h1));
        unsigned l2 = rne_bf16(w2 - bf16_dec(h2)), l3 = rne_bf16(w3 - bf16_dec(h3));
        unsigned d0 = h0 | (h1 << 16), d1 = h2 | (h3 << 16);
        unsigned d2 = l0 | (l1 << 16), d3 = l2 | (l3 << 16);
        uint4* wr = (s == 0) ? wpred : wtgt;
        wr[i * 2 + 0] = make_uint4(d0, d1, d2, d3);            // k0-7: [ah, al]
        wr[i * 2 + 1] = make_uint4(d0, d1, onepk, npk);        // k8-15: [ah, 1,1, Pnh,Pnl]

        // plain col-side record (from this point set) — FIXED: pred->ppred, tgt->ptgt
        unsigned g0 = rne_bf16(v.x), g1 = rne_bf16(v.y), g2 = rne_bf16(v.z), g3 = rne_bf16(v.w);
        unsigned m0 = rne_bf16(v.x - bf16_dec(g0)), m1 = rne_bf16(v.y - bf16_dec(g1));
        unsigned m2 = rne_bf16(v.z - bf16_dec(g2)), m3 = rne_bf16(v.w - bf16_dec(g3));
        unsigned e0 = g0 | (g1 << 16), e1 = g2 | (g3 << 16);
        unsigned e2 = m0 | (m1 << 16), e3 = m2 | (m3 << 16);
        uint4* pr = (s == 0) ? ppred : ptgt;
        pr[i * 2 + 0] = make_uint4(e0, e1, e0, e1);            // k0-7: [bh, bh]
        pr[i * 2 + 1] = make_uint4(e2, e3, npk, onepk);        // k8-15: [bl, Tnh,Tnl, 1,1]
    }
}

__global__ __launch_bounds__(256, 4) void chamfer_mfma_kernel(
    const bf16x8* __restrict__ wpred, const bf16x8* __restrict__ ptgt,
    const bf16x8* __restrict__ wtgt,  const bf16x8* __restrict__ ppred,
    unsigned int* __restrict__ minbuf)
{
    const bf16x8* rowRec; const bf16x8* colRec; unsigned int* mb;
    if (blockIdx.z == 0) { rowRec = wpred; colRec = ptgt;  mb = minbuf; }
    else                 { rowRec = wtgt;  colRec = ppred; mb = minbuf + NPTS; }

    const int lane = threadIdx.x & 63;
    const int wave = threadIdx.x >> 6;
    const int half = lane >> 5;     // selects k0-7 vs k8-15 record
    const int lid  = lane & 31;

    const int rowBase = blockIdx.x * RPB + wave * RPW;
    const int colBase = blockIdx.y * CHUNK;

    // A-fragments for this wave's 64 rows (lane -> row = lid, regs -> k)
    bf16x8 a0 = rowRec[(rowBase +      lid) * 2 + half];
    bf16x8 a1 = rowRec[(rowBase + 32 + lid) * 2 + half];

    float m0[16], m1[16];
#pragma unroll
    for (int r = 0; r < 16; ++r) { m0[r] = 3.0e38f; m1[r] = 3.0e38f; }

    const bf16x8* bp = colRec + (colBase + lid) * 2 + half;

#pragma unroll 2
    for (int t = 0; t < CHUNK / 32; ++t) {
        bf16x8 b = bp[t * 64];
        f32x16 acc0 = __builtin_amdgcn_mfma_f32_32x32x16_bf16(a0, b, (f32x16)(0.0f), 0, 0, 0);
        f32x16 acc1 = __builtin_amdgcn_mfma_f32_32x32x16_bf16(a1, b, (f32x16)(0.0f), 0, 0, 0);
#pragma unroll
        for (int r = 0; r < 16; ++r) {
            m0[r] = fminf(m0[r], acc0[r]);
            m1[r] = fminf(m1[r], acc1[r]);
        }
    }

    // cross-lane min over the 32 col-lanes; C/D layout: col=lane&31,
    // row=(reg&3)+8*(reg>>2)+4*(lane>>5)
    __shared__ float red[RPB];
#pragma unroll
    for (int r = 0; r < 16; ++r) {
        float v0 = m0[r], v1 = m1[r];
        v0 = fminf(v0, __shfl_xor(v0, 16)); v1 = fminf(v1, __shfl_xor(v1, 16));
        v0 = fminf(v0, __shfl_xor(v0, 8));  v1 = fminf(v1, __shfl_xor(v1, 8));
        v0 = fminf(v0, __shfl_xor(v0, 4));  v1 = fminf(v1, __shfl_xor(v1, 4));
        v0 = fminf(v0, __shfl_xor(v0, 2));  v1 = fminf(v1, __shfl_xor(v1, 2));
        v0 = fminf(v0, __shfl_xor(v0, 1));  v1 = fminf(v1, __shfl_xor(v1, 1));
        if (lid == 0) {
            int row = (r & 3) + 8 * (r >> 2) + 4 * half;
            red[wave * RPW + row]      = v0;
            red[wave * RPW + 32 + row] = v1;
        }
    }
    __syncthreads();
    {
        float v = fmaxf(red[threadIdx.x], 0.0f);   // ref clamps dist >= 0
        atomicMin(&mb[blockIdx.x * RPB + threadIdx.x], __float_as_uint(v));
    }
}

__global__ __launch_bounds__(1024) void chamfer_reduce_kernel(
    const unsigned int* __restrict__ minbuf, float* __restrict__ out)
{
    __shared__ float red[16];
    float s = 0.0f;
    for (int i = threadIdx.x; i < 2 * NPTS; i += 1024)
        s += __uint_as_float(minbuf[i]);
#pragma unroll
    for (int off = 32; off > 0; off >>= 1)
        s += __shfl_down(s, off);
    const int wave = threadIdx.x >> 6;
    const int lane = threadIdx.x & 63;
    if (lane == 0) red[wave] = s;
    __syncthreads();
    if (threadIdx.x == 0) {
        float t = 0.0f;
#pragma unroll
        for (int w = 0; w < 16; ++w) t += red[w];
        out[0] = t * (1.0f / (float)NPTS);
    }
}

extern "C" void kernel_launch(void* const* d_in, const int* in_sizes, int n_in,
                              void* d_out, int out_size, void* d_ws, size_t ws_size,
                              hipStream_t stream) {
    const float4* pred = (const float4*)d_in[0];
    const float4* tgt  = (const float4*)d_in[1];

    unsigned int* minbuf = (unsigned int*)d_ws;                     // 128 KB
    uint4* wpred = (uint4*)((char*)d_ws + 2 * NPTS * 4);            // 512 KB each
    uint4* ptgt  = wpred + 2 * NPTS;
    uint4* wtgt  = ptgt  + 2 * NPTS;
    uint4* ppred = wtgt  + 2 * NPTS;

    hipMemsetAsync(minbuf, 0x7f, 2 * NPTS * sizeof(unsigned int), stream);
    prep_kernel<<<NPTS / 256, 256, 0, stream>>>(pred, tgt, wpred, ptgt, wtgt, ppred);

    dim3 grid(NRB, NCHUNK, 2);   // (64, 8, 2) = 1024 blocks
    chamfer_mfma_kernel<<<grid, 256, 0, stream>>>(
        (const bf16x8*)wpred, (const bf16x8*)ptgt,
        (const bf16x8*)wtgt,  (const bf16x8*)ppred, minbuf);

    chamfer_reduce_kernel<<<1, 1024, 0, stream>>>(minbuf, (float*)d_out);
}

// Round 6
// 34.906 us; speedup vs baseline: 2.0045x; 1.2619x over previous
//
#include <hip/hip_runtime.h>

#define NPTS   16384
#define RPB    256      // rows per block (4 waves x 64)
#define RPW    64       // rows per wave (2 row-tiles of 32)
#define CHUNK  2048     // cols per block sweep
#define NCHUNK (NPTS / CHUNK)   // 8
#define NRB    (NPTS / RPB)     // 64

typedef short  bf16x8 __attribute__((ext_vector_type(8)));
typedef float  f32x16 __attribute__((ext_vector_type(16)));

// ---- bf16 split helpers (RNE) ----
__device__ __forceinline__ unsigned rne_bf16(float f) {
    unsigned u = __float_as_uint(f);
    return (u + 0x7fffu + ((u >> 16) & 1u)) >> 16;
}
__device__ __forceinline__ float bf16_dec(unsigned h) {
    return __uint_as_float(h << 16);
}
#define ONE_BF 0x3f80u

// K=16 slot map (A = row side / weighted, B = col side / plain):
//  k0-3 : ah*bh   k4-7: al*bh   k8-11: ah*bl
//  k12  : 1*Tnh   k13 : 1*Tnl   k14: Pnh*1   k15: Pnl*1
// => acc = hi-precision dot + Tn_j + Pn_i = combined(i,j) directly.
// Record layout per point: 2 x bf16x8 (lane<32 reads rec[0], lane>=32 rec[1]).

__global__ __launch_bounds__(256) void prep_kernel(
    const float4* __restrict__ pred, const float4* __restrict__ tgt,
    uint4* __restrict__ wpred, uint4* __restrict__ ptgt,
    uint4* __restrict__ wtgt,  uint4* __restrict__ ppred,
    unsigned int* __restrict__ minbuf)
{
    int i = blockIdx.x * 256 + threadIdx.x;
    if (i >= NPTS) return;

    // init min buffers (replaces hipMemsetAsync dispatch)
    minbuf[i]        = 0x7f7f7f7fu;   // 3.39e38f
    minbuf[i + NPTS] = 0x7f7f7f7fu;

    float4 pts[2] = { pred[i], tgt[i] };

#pragma unroll
    for (int s = 0; s < 2; ++s) {
        float4 v = pts[s];
        float n = fmaf(v.x, v.x, fmaf(v.y, v.y, fmaf(v.z, v.z, 0.5f * v.w * v.w)));
        unsigned nh = rne_bf16(n);
        unsigned nl = rne_bf16(n - bf16_dec(nh));
        unsigned npk = nh | (nl << 16);
        unsigned onepk = ONE_BF | (ONE_BF << 16);

        // weighted row-side record
        float w0 = -2.0f * v.x, w1 = -2.0f * v.y, w2 = -2.0f * v.z, w3 = -v.w;
        unsigned h0 = rne_bf16(w0), h1 = rne_bf16(w1), h2 = rne_bf16(w2), h3 = rne_bf16(w3);
        unsigned l0 = rne_bf16(w0 - bf16_dec(h0)), l1 = rne_bf16(w1 - bf16_dec(h1));
        unsigned l2 = rne_bf16(w2 - bf16_dec(h2)), l3 = rne_bf16(w3 - bf16_dec(h3));
        unsigned d0 = h0 | (h1 << 16), d1 = h2 | (h3 << 16);
        unsigned d2 = l0 | (l1 << 16), d3 = l2 | (l3 << 16);
        uint4* wr = (s == 0) ? wpred : wtgt;
        wr[i * 2 + 0] = make_uint4(d0, d1, d2, d3);            // k0-7: [ah, al]
        wr[i * 2 + 1] = make_uint4(d0, d1, onepk, npk);        // k8-15: [ah, 1,1, Pnh,Pnl]

        // plain col-side record
        unsigned g0 = rne_bf16(v.x), g1 = rne_bf16(v.y), g2 = rne_bf16(v.z), g3 = rne_bf16(v.w);
        unsigned m0 = rne_bf16(v.x - bf16_dec(g0)), m1 = rne_bf16(v.y - bf16_dec(g1));
        unsigned m2 = rne_bf16(v.z - bf16_dec(g2)), m3 = rne_bf16(v.w - bf16_dec(g3));
        unsigned e0 = g0 | (g1 << 16), e1 = g2 | (g3 << 16);
        unsigned e2 = m0 | (m1 << 16), e3 = m2 | (m3 << 16);
        uint4* pr = (s == 0) ? ppred : ptgt;
        pr[i * 2 + 0] = make_uint4(e0, e1, e0, e1);            // k0-7: [bh, bh]
        pr[i * 2 + 1] = make_uint4(e2, e3, npk, onepk);        // k8-15: [bl, Tnh,Tnl, 1,1]
    }
}

__global__ __launch_bounds__(256, 4) void chamfer_mfma_kernel(
    const bf16x8* __restrict__ wpred, const bf16x8* __restrict__ ptgt,
    const bf16x8* __restrict__ wtgt,  const bf16x8* __restrict__ ppred,
    unsigned int* __restrict__ minbuf)
{
    const bf16x8* rowRec; const bf16x8* colRec; unsigned int* mb;
    if (blockIdx.z == 0) { rowRec = wpred; colRec = ptgt;  mb = minbuf; }
    else                 { rowRec = wtgt;  colRec = ppred; mb = minbuf + NPTS; }

    const int lane = threadIdx.x & 63;
    const int wave = threadIdx.x >> 6;
    const int half = lane >> 5;     // selects k0-7 vs k8-15 record
    const int lid  = lane & 31;

    const int rowBase = blockIdx.x * RPB + wave * RPW;
    const int colBase = blockIdx.y * CHUNK;

    // A-fragments for this wave's 64 rows (lane -> row = lid, regs -> k)
    bf16x8 a0 = rowRec[(rowBase +      lid) * 2 + half];
    bf16x8 a1 = rowRec[(rowBase + 32 + lid) * 2 + half];

    float m0[16], m1[16];
#pragma unroll
    for (int r = 0; r < 16; ++r) { m0[r] = 3.0e38f; m1[r] = 3.0e38f; }

    const bf16x8* bp = colRec + (colBase + lid) * 2 + half;
    const f32x16 kZero = (f32x16)(0.0f);

    // pair two j-iterations: merge = fminf(fminf(a,b),m) -> v_min3_f32
    // (compiler-generated so MFMA->VALU hazard nops are inserted correctly;
    //  hand-asm v_min3 here read in-flight MFMA results and corrupted mins)
#pragma unroll 2
    for (int t = 0; t < CHUNK / 64; ++t) {
        bf16x8 bA = bp[t * 128];
        bf16x8 bB = bp[t * 128 + 64];
        // tile 0 (rows 0-31)
        f32x16 accA = __builtin_amdgcn_mfma_f32_32x32x16_bf16(a0, bA, kZero, 0, 0, 0);
        f32x16 accB = __builtin_amdgcn_mfma_f32_32x32x16_bf16(a0, bB, kZero, 0, 0, 0);
#pragma unroll
        for (int r = 0; r < 16; ++r)
            m0[r] = fminf(fminf(accA[r], accB[r]), m0[r]);
        // tile 1 (rows 32-63)
        f32x16 accC = __builtin_amdgcn_mfma_f32_32x32x16_bf16(a1, bA, kZero, 0, 0, 0);
        f32x16 accD = __builtin_amdgcn_mfma_f32_32x32x16_bf16(a1, bB, kZero, 0, 0, 0);
#pragma unroll
        for (int r = 0; r < 16; ++r)
            m1[r] = fminf(fminf(accC[r], accD[r]), m1[r]);
    }

    // cross-lane min over the 32 col-lanes; C/D layout: col=lane&31,
    // row=(reg&3)+8*(reg>>2)+4*(lane>>5)
    __shared__ float red[RPB];
#pragma unroll
    for (int r = 0; r < 16; ++r) {
        float v0 = m0[r], v1 = m1[r];
        v0 = fminf(v0, __shfl_xor(v0, 16)); v1 = fminf(v1, __shfl_xor(v1, 16));
        v0 = fminf(v0, __shfl_xor(v0, 8));  v1 = fminf(v1, __shfl_xor(v1, 8));
        v0 = fminf(v0, __shfl_xor(v0, 4));  v1 = fminf(v1, __shfl_xor(v1, 4));
        v0 = fminf(v0, __shfl_xor(v0, 2));  v1 = fminf(v1, __shfl_xor(v1, 2));
        v0 = fminf(v0, __shfl_xor(v0, 1));  v1 = fminf(v1, __shfl_xor(v1, 1));
        if (lid == 0) {
            int row = (r & 3) + 8 * (r >> 2) + 4 * half;
            red[wave * RPW + row]      = v0;
            red[wave * RPW + 32 + row] = v1;
        }
    }
    __syncthreads();
    {
        float v = fmaxf(red[threadIdx.x], 0.0f);   // ref clamps dist >= 0
        atomicMin(&mb[blockIdx.x * RPB + threadIdx.x], __float_as_uint(v));
    }
}

__global__ __launch_bounds__(1024) void chamfer_reduce_kernel(
    const unsigned int* __restrict__ minbuf, float* __restrict__ out)
{
    __shared__ float red[16];
    const uint4* mb4 = (const uint4*)minbuf;
    float s = 0.0f;
#pragma unroll
    for (int it = 0; it < (2 * NPTS / 4) / 1024; ++it) {
        uint4 u = mb4[it * 1024 + threadIdx.x];
        s += __uint_as_float(u.x) + __uint_as_float(u.y)
           + __uint_as_float(u.z) + __uint_as_float(u.w);
    }
#pragma unroll
    for (int off = 32; off > 0; off >>= 1)
        s += __shfl_down(s, off);
    const int wave = threadIdx.x >> 6;
    const int lane = threadIdx.x & 63;
    if (lane == 0) red[wave] = s;
    __syncthreads();
    if (threadIdx.x == 0) {
        float t = 0.0f;
#pragma unroll
        for (int w = 0; w < 16; ++w) t += red[w];
        out[0] = t * (1.0f / (float)NPTS);
    }
}

extern "C" void kernel_launch(void* const* d_in, const int* in_sizes, int n_in,
                              void* d_out, int out_size, void* d_ws, size_t ws_size,
                              hipStream_t stream) {
    const float4* pred = (const float4*)d_in[0];
    const float4* tgt  = (const float4*)d_in[1];

    unsigned int* minbuf = (unsigned int*)d_ws;                     // 128 KB
    uint4* wpred = (uint4*)((char*)d_ws + 2 * NPTS * 4);            // 512 KB each
    uint4* ptgt  = wpred + 2 * NPTS;
    uint4* wtgt  = ptgt  + 2 * NPTS;
    uint4* ppred = wtgt  + 2 * NPTS;

    prep_kernel<<<NPTS / 256, 256, 0, stream>>>(pred, tgt, wpred, ptgt, wtgt,
                                                ppred, minbuf);

    dim3 grid(NRB, NCHUNK, 2);   // (64, 8, 2) = 1024 blocks
    chamfer_mfma_kernel<<<grid, 256, 0, stream>>>(
        (const bf16x8*)wpred, (const bf16x8*)ptgt,
        (const bf16x8*)wtgt,  (const bf16x8*)ppred, minbuf);

    chamfer_reduce_kernel<<<1, 1024, 0, stream>>>(minbuf, (float*)d_out);
}